// Round 2
// baseline (750.198 us; speedup 1.0000x reference)
//
#include <hip/hip_runtime.h>
#include <hip/hip_bf16.h>
#include <math.h>

// Mixtral-style top-2 MoE. T=2048, H=1024, I=2816, E=8, top_k=2.
// ALL input tensors and the output are fp32 (per reference dtypes).
// Compute path: fp32 -> bf16 (RNE, during LDS staging) -> bf16 MFMA -> fp32 acc.

#define T_TOK 2048
#define H_DIM 1024
#define I_DIM 2816
#define E_NUM 8

typedef __attribute__((ext_vector_type(8))) short bf16x8;
typedef __attribute__((ext_vector_type(4))) float f32x4;

// ---- workspace layout (bytes) ----
#define WS_COUNTS 0
#define WS_BASE   64
#define WS_ROWTOK 1024
#define WS_WEIGHT 66560
#define WS_ACT    131072ull                    // bf16 A [4096][I]  (23.07 MB)
#define WS_Y      (131072ull + 23068672ull)    // fp32 Y [4096][H]  (16.78 MB)

__device__ __forceinline__ unsigned short f2b(float f) {
    union { float f; unsigned int i; } c;
    c.f = f;
    unsigned int x = c.i;
    unsigned int r = x + 0x7FFFu + ((x >> 16) & 1u);  // RNE
    return (unsigned short)(r >> 16);
}

// convert 8 consecutive fp32 (two float4) to bf16x8
__device__ __forceinline__ bf16x8 cvt8(const float* __restrict__ p) {
    float4 a = *(const float4*)p;
    float4 b = *(const float4*)(p + 4);
    bf16x8 o;
    o[0] = (short)f2b(a.x); o[1] = (short)f2b(a.y);
    o[2] = (short)f2b(a.z); o[3] = (short)f2b(a.w);
    o[4] = (short)f2b(b.x); o[5] = (short)f2b(b.y);
    o[6] = (short)f2b(b.z); o[7] = (short)f2b(b.w);
    return o;
}

// -------- 1. routing: softmax -> top-2 -> renorm -> per-expert lists --------
__global__ void k_route(const float* __restrict__ logits,
                        int* __restrict__ counts,
                        unsigned int* __restrict__ rowtok,
                        float* __restrict__ weight) {
    int t = blockIdx.x * blockDim.x + threadIdx.x;
    if (t >= T_TOK) return;
    const float* p = logits + t * E_NUM;
    float l[E_NUM];
#pragma unroll
    for (int i = 0; i < E_NUM; i++) l[i] = p[i];
    float m = l[0];
#pragma unroll
    for (int i = 1; i < E_NUM; i++) m = fmaxf(m, l[i]);
    float e[E_NUM];
#pragma unroll
    for (int i = 0; i < E_NUM; i++) e[i] = expf(l[i] - m);
    int i0 = 0; float p0 = e[0];
#pragma unroll
    for (int i = 1; i < E_NUM; i++) if (e[i] > p0) { p0 = e[i]; i0 = i; }
    int i1 = -1; float p1 = -1.f;
#pragma unroll
    for (int i = 0; i < E_NUM; i++) if (i != i0 && e[i] > p1) { p1 = e[i]; i1 = i; }
    float s = p0 + p1;
    weight[t * 2 + 0] = p0 / s;   // exact fp32 (reference astype(fp32) is no-op)
    weight[t * 2 + 1] = p1 / s;
    int q0 = atomicAdd(&counts[i0], 1);
    rowtok[i0 * T_TOK + q0] = (unsigned)(t * 2 + 0);
    int q1 = atomicAdd(&counts[i1], 1);
    rowtok[i1 * T_TOK + q1] = (unsigned)(t * 2 + 1);
}

// -------- 2. exclusive prefix over 8 counts --------
__global__ void k_prefix(const int* __restrict__ counts, int* __restrict__ base) {
    if (threadIdx.x == 0) {
        int s = 0;
        for (int e = 0; e < E_NUM; e++) { base[e] = s; s += counts[e]; }
    }
}

// -------- 3. fused gate/up GEMM: A = silu(Xe W1^T) * (Xe W3^T) --------
// tile: 64(M) x 128(N over I), BK=64. 4 waves in 2x2. Each wave: 32x64.
#define BK 64
#define LDSP 72  // 64 + 8 pad (16B-aligned rows, breaks pow2 bank stride)

__global__ __launch_bounds__(256) void k_gate_up(
    const float* __restrict__ X,    // [T][H] fp32
    const float* __restrict__ W1,   // [E][I][H] fp32
    const float* __restrict__ W3,   // [E][I][H] fp32
    const int* __restrict__ counts, const int* __restrict__ base,
    const unsigned int* __restrict__ rowtok,
    unsigned short* __restrict__ Aout)       // [4096][I] bf16 compacted
{
    const int e = blockIdx.z;
    const int cnt = counts[e];
    const int m0 = blockIdx.y * 64;
    if (m0 >= cnt) return;
    const int n0 = blockIdx.x * 128;
    const int b0 = base[e];

    __shared__ unsigned short Xs[64][LDSP];
    __shared__ unsigned short W1s[128][LDSP];
    __shared__ unsigned short W3s[128][LDSP];
    __shared__ int toks[64];

    const int tid = threadIdx.x;
    if (tid < 64) {
        int r = m0 + tid;
        if (r >= cnt) r = cnt - 1;  // clamp tail; stores are guarded
        toks[tid] = (int)(rowtok[e * T_TOK + r] >> 1);
    }
    __syncthreads();

    const int wv = tid >> 6, lane = tid & 63;
    const int lr = lane & 15, lq = lane >> 4;
    const int wm = (wv >> 1) * 32, wn = (wv & 1) * 64;

    f32x4 accG[2][4], accU[2][4];
#pragma unroll
    for (int i = 0; i < 2; i++)
#pragma unroll
        for (int j = 0; j < 4; j++) {
            accG[i][j] = (f32x4){0.f, 0.f, 0.f, 0.f};
            accU[i][j] = (f32x4){0.f, 0.f, 0.f, 0.f};
        }

    const size_t wbase = ((size_t)e * I_DIM + n0) * H_DIM;

    for (int k0 = 0; k0 < H_DIM; k0 += BK) {
        // stage X tile: 64 rows x 64 elems; 8 fp32 -> bf16x8 per thread-chunk
#pragma unroll
        for (int it = 0; it < 2; ++it) {
            int idx = tid + it * 256;
            int r = idx >> 3, c = (idx & 7) * 8;
            *(bf16x8*)&Xs[r][c] = cvt8(X + (size_t)toks[r] * H_DIM + k0 + c);
        }
#pragma unroll
        for (int it = 0; it < 4; ++it) {
            int idx = tid + it * 256;
            int r = idx >> 3, c = (idx & 7) * 8;
            size_t off = wbase + (size_t)r * H_DIM + k0 + c;
            *(bf16x8*)&W1s[r][c] = cvt8(W1 + off);
            *(bf16x8*)&W3s[r][c] = cvt8(W3 + off);
        }
        __syncthreads();
#pragma unroll
        for (int kk = 0; kk < BK; kk += 32) {
            bf16x8 af[2];
#pragma unroll
            for (int mi = 0; mi < 2; mi++)
                af[mi] = *(const bf16x8*)&Xs[wm + mi * 16 + lr][kk + lq * 8];
#pragma unroll
            for (int ni = 0; ni < 4; ni++) {
                bf16x8 b1 = *(const bf16x8*)&W1s[wn + ni * 16 + lr][kk + lq * 8];
                bf16x8 b3 = *(const bf16x8*)&W3s[wn + ni * 16 + lr][kk + lq * 8];
#pragma unroll
                for (int mi = 0; mi < 2; mi++) {
                    accG[mi][ni] = __builtin_amdgcn_mfma_f32_16x16x32_bf16(
                        af[mi], b1, accG[mi][ni], 0, 0, 0);
                    accU[mi][ni] = __builtin_amdgcn_mfma_f32_16x16x32_bf16(
                        af[mi], b3, accU[mi][ni], 0, 0, 0);
                }
            }
        }
        __syncthreads();
    }

    // epilogue: silu(g)*u -> bf16 -> compacted A
#pragma unroll
    for (int mi = 0; mi < 2; mi++) {
#pragma unroll
        for (int r = 0; r < 4; r++) {
            int row = m0 + wm + mi * 16 + lq * 4 + r;
            if (row < cnt) {
                size_t orow = (size_t)(b0 + row) * I_DIM + n0 + wn;
#pragma unroll
                for (int ni = 0; ni < 4; ni++) {
                    float g = accG[mi][ni][r];
                    float u = accU[mi][ni][r];
                    float a = (g / (1.f + __expf(-g))) * u;
                    Aout[orow + ni * 16 + lr] = f2b(a);
                }
            }
        }
    }
}

// -------- 4. down GEMM: Y = (A W2^T) * route_weight, scattered to (t,slot) --------
__global__ __launch_bounds__(256) void k_down(
    const unsigned short* __restrict__ A,    // [4096][I] bf16 compacted
    const float* __restrict__ W2,            // [E][H][I] fp32
    const int* __restrict__ counts, const int* __restrict__ base,
    const unsigned int* __restrict__ rowtok,
    const float* __restrict__ weight,
    float* __restrict__ Y)                   // [4096][H] fp32, row = t*2+slot
{
    const int e = blockIdx.z;
    const int cnt = counts[e];
    const int m0 = blockIdx.y * 64;
    if (m0 >= cnt) return;
    const int n0 = blockIdx.x * 128;
    const int b0 = base[e];

    __shared__ unsigned short As[64][LDSP];
    __shared__ unsigned short Ws[128][LDSP];

    const int tid = threadIdx.x;
    const int wv = tid >> 6, lane = tid & 63;
    const int lr = lane & 15, lq = lane >> 4;
    const int wm = (wv >> 1) * 32, wn = (wv & 1) * 64;

    f32x4 acc[2][4];
#pragma unroll
    for (int i = 0; i < 2; i++)
#pragma unroll
        for (int j = 0; j < 4; j++) acc[i][j] = (f32x4){0.f, 0.f, 0.f, 0.f};

    const size_t wbase = ((size_t)e * H_DIM + n0) * I_DIM;

    for (int k0 = 0; k0 < I_DIM; k0 += BK) {
#pragma unroll
        for (int it = 0; it < 2; ++it) {
            int idx = tid + it * 256;
            int r = idx >> 3, c = (idx & 7) * 8;
            int rr = m0 + r;
            if (rr >= cnt) rr = cnt - 1;
            *(bf16x8*)&As[r][c] =
                *(const bf16x8*)(A + (size_t)(b0 + rr) * I_DIM + k0 + c);
        }
#pragma unroll
        for (int it = 0; it < 4; ++it) {
            int idx = tid + it * 256;
            int r = idx >> 3, c = (idx & 7) * 8;
            *(bf16x8*)&Ws[r][c] = cvt8(W2 + wbase + (size_t)r * I_DIM + k0 + c);
        }
        __syncthreads();
#pragma unroll
        for (int kk = 0; kk < BK; kk += 32) {
            bf16x8 af[2];
#pragma unroll
            for (int mi = 0; mi < 2; mi++)
                af[mi] = *(const bf16x8*)&As[wm + mi * 16 + lr][kk + lq * 8];
#pragma unroll
            for (int ni = 0; ni < 4; ni++) {
                bf16x8 b = *(const bf16x8*)&Ws[wn + ni * 16 + lr][kk + lq * 8];
#pragma unroll
                for (int mi = 0; mi < 2; mi++)
                    acc[mi][ni] = __builtin_amdgcn_mfma_f32_16x16x32_bf16(
                        af[mi], b, acc[mi][ni], 0, 0, 0);
            }
        }
        __syncthreads();
    }

#pragma unroll
    for (int mi = 0; mi < 2; mi++) {
#pragma unroll
        for (int r = 0; r < 4; r++) {
            int row = m0 + wm + mi * 16 + lq * 4 + r;
            if (row < cnt) {
                unsigned rt = rowtok[e * T_TOK + row];
                float w = weight[rt];
                size_t orow = (size_t)rt * H_DIM + n0 + wn;
#pragma unroll
                for (int ni = 0; ni < 4; ni++)
                    Y[orow + ni * 16 + lr] = w * acc[mi][ni][r];
            }
        }
    }
}

// -------- 5. combine slots -> fp32 out --------
__global__ void k_combine(const float* __restrict__ Y,
                          float* __restrict__ out) {
    int g = blockIdx.x * blockDim.x + threadIdx.x;  // 2048*256 total
    int t = g >> 8, c4 = g & 255;
    const float4* y0 = (const float4*)(Y + (size_t)(t * 2) * H_DIM);
    const float4* y1 = (const float4*)(Y + (size_t)(t * 2 + 1) * H_DIM);
    float4 a = y0[c4], b = y1[c4];
    float4 o;
    o.x = a.x + b.x; o.y = a.y + b.y; o.z = a.z + b.z; o.w = a.w + b.w;
    *(float4*)(out + (size_t)t * H_DIM + c4 * 4) = o;
}

extern "C" void kernel_launch(void* const* d_in, const int* in_sizes, int n_in,
                              void* d_out, int out_size, void* d_ws, size_t ws_size,
                              hipStream_t stream) {
    (void)in_sizes; (void)n_in; (void)out_size; (void)ws_size;
    const float* X  = (const float*)d_in[0];
    const float* RL = (const float*)d_in[1];
    const float* W1 = (const float*)d_in[2];
    const float* W3 = (const float*)d_in[3];
    const float* W2 = (const float*)d_in[4];
    float* out = (float*)d_out;

    char* ws = (char*)d_ws;
    int* counts          = (int*)(ws + WS_COUNTS);
    int* base            = (int*)(ws + WS_BASE);
    unsigned int* rowtok = (unsigned int*)(ws + WS_ROWTOK);
    float* weight        = (float*)(ws + WS_WEIGHT);
    unsigned short* Aact = (unsigned short*)(ws + WS_ACT);
    float* Y             = (float*)(ws + WS_Y);

    hipMemsetAsync(counts, 0, 64, stream);
    hipLaunchKernelGGL(k_route, dim3(T_TOK / 256), dim3(256), 0, stream,
                       RL, counts, rowtok, weight);
    hipLaunchKernelGGL(k_prefix, dim3(1), dim3(64), 0, stream, counts, base);
    hipLaunchKernelGGL(k_gate_up, dim3(I_DIM / 128, T_TOK / 64, E_NUM), dim3(256),
                       0, stream, X, W1, W3, counts, base, rowtok, Aact);
    hipLaunchKernelGGL(k_down, dim3(H_DIM / 128, T_TOK / 64, E_NUM), dim3(256),
                       0, stream, Aact, W2, counts, base, rowtok, weight, Y);
    hipLaunchKernelGGL(k_combine, dim3(T_TOK), dim3(256), 0, stream, Y, out);
}

// Round 3
// 518.964 us; speedup vs baseline: 1.4456x; 1.4456x over previous
//
#include <hip/hip_runtime.h>
#include <hip/hip_bf16.h>
#include <math.h>

// Mixtral-style top-2 MoE. T=2048, H=1024, I=2816, E=8, top_k=2.
// All inputs/outputs fp32. Fast path: pre-convert W,X to bf16 in ws, then
// m97-style MFMA GEMMs (global_load_lds width=16, XOR-swizzled LDS).
// Fallback (ws too small): R1 path (cvt-in-staging), known-passing.

#define T_TOK 2048
#define H_DIM 1024
#define I_DIM 2816
#define E_NUM 8

typedef __attribute__((ext_vector_type(8))) short bf16x8;
typedef __attribute__((ext_vector_type(4))) float f32x4;

// ---- shared low ws region ----
#define WS_COUNTS 0
#define WS_BASE   64
#define WS_ROWTOK 1024
#define WS_WEIGHT 66560
// ---- fast path ws ----
#define WSF_X   131072ull                       // bf16 X  [2048][1024]   4 MB
#define WSF_W1  (WSF_X  + 4194304ull)           // bf16 W1 [8][2816][1024] 46.1 MB
#define WSF_W3  (WSF_W1 + 46137344ull)
#define WSF_W2  (WSF_W3 + 46137344ull)
#define WSF_A   (WSF_W2 + 46137344ull)          // bf16 A  [4096][2816]  23.1 MB
#define WSF_NEED (WSF_A + 23068672ull)          // = 165,806,080 B
// ---- fallback ws ----
#define WS_ACT    131072ull
#define WS_Y      (131072ull + 23068672ull)

__device__ __forceinline__ unsigned short f2b(float f) {
    union { float f; unsigned int i; } c;
    c.f = f;
    unsigned int x = c.i;
    unsigned int r = x + 0x7FFFu + ((x >> 16) & 1u);  // RNE
    return (unsigned short)(r >> 16);
}

__device__ __forceinline__ bf16x8 cvt8(const float* __restrict__ p) {
    float4 a = *(const float4*)p;
    float4 b = *(const float4*)(p + 4);
    bf16x8 o;
    o[0] = (short)f2b(a.x); o[1] = (short)f2b(a.y);
    o[2] = (short)f2b(a.z); o[3] = (short)f2b(a.w);
    o[4] = (short)f2b(b.x); o[5] = (short)f2b(b.y);
    o[6] = (short)f2b(b.z); o[7] = (short)f2b(b.w);
    return o;
}

// async global->LDS, 16 bytes per lane. LDS dst must be wave-uniform-base + lane*16.
__device__ __forceinline__ void gl_lds16(const void* g, void* l) {
    __builtin_amdgcn_global_load_lds(
        (const __attribute__((address_space(1))) unsigned int*)g,
        (__attribute__((address_space(3))) unsigned int*)l, 16, 0, 0);
}

// -------- 1. routing --------
__global__ void k_route(const float* __restrict__ logits,
                        int* __restrict__ counts,
                        unsigned int* __restrict__ rowtok,
                        float* __restrict__ weight) {
    int t = blockIdx.x * blockDim.x + threadIdx.x;
    if (t >= T_TOK) return;
    const float* p = logits + t * E_NUM;
    float l[E_NUM];
#pragma unroll
    for (int i = 0; i < E_NUM; i++) l[i] = p[i];
    float m = l[0];
#pragma unroll
    for (int i = 1; i < E_NUM; i++) m = fmaxf(m, l[i]);
    float e[E_NUM];
#pragma unroll
    for (int i = 0; i < E_NUM; i++) e[i] = expf(l[i] - m);
    int i0 = 0; float p0 = e[0];
#pragma unroll
    for (int i = 1; i < E_NUM; i++) if (e[i] > p0) { p0 = e[i]; i0 = i; }
    int i1 = -1; float p1 = -1.f;
#pragma unroll
    for (int i = 0; i < E_NUM; i++) if (i != i0 && e[i] > p1) { p1 = e[i]; i1 = i; }
    float s = p0 + p1;
    weight[t * 2 + 0] = p0 / s;
    weight[t * 2 + 1] = p1 / s;
    int q0 = atomicAdd(&counts[i0], 1);
    rowtok[i0 * T_TOK + q0] = (unsigned)(t * 2 + 0);
    int q1 = atomicAdd(&counts[i1], 1);
    rowtok[i1 * T_TOK + q1] = (unsigned)(t * 2 + 1);
}

// -------- 2. prefix --------
__global__ void k_prefix(const int* __restrict__ counts, int* __restrict__ base) {
    if (threadIdx.x == 0) {
        int s = 0;
        for (int e = 0; e < E_NUM; e++) { base[e] = s; s += counts[e]; }
    }
}

// -------- fast path --------

// fp32 -> bf16 bulk convert: W1,W3,W2 (11264 blocks each), X (1024 blocks)
__global__ __launch_bounds__(256) void k_cvt(
    const float* __restrict__ W1, const float* __restrict__ W3,
    const float* __restrict__ W2, const float* __restrict__ X,
    unsigned short* __restrict__ W1b, unsigned short* __restrict__ W3b,
    unsigned short* __restrict__ W2b, unsigned short* __restrict__ Xb) {
    int b = blockIdx.x;
    const float* src; unsigned short* dst; int lb;
    if (b < 11264)      { src = W1; dst = W1b; lb = b; }
    else if (b < 22528) { src = W3; dst = W3b; lb = b - 11264; }
    else if (b < 33792) { src = W2; dst = W2b; lb = b - 22528; }
    else                { src = X;  dst = Xb;  lb = b - 33792; }
    size_t i = ((size_t)lb * 256 + threadIdx.x) * 8;
    *(bf16x8*)(dst + i) = cvt8(src + i);
}

// gate/up GEMM, fast: 128x128 tile, BK=64, 4 waves (2x2 of 64x64).
// LDS tiles [128][64] bf16, XOR-swizzled: physical 16B-chunk = logical ^ (row&7).
__global__ __launch_bounds__(256) void k_gate_up_f(
    const unsigned short* __restrict__ Xb,
    const unsigned short* __restrict__ W1b,
    const unsigned short* __restrict__ W3b,
    const int* __restrict__ counts, const int* __restrict__ base,
    const unsigned int* __restrict__ rowtok,
    unsigned short* __restrict__ Aout) {
    const int e = blockIdx.z;
    const int cnt = counts[e];
    const int m0 = blockIdx.y * 128;
    if (m0 >= cnt) return;
    const int n0 = blockIdx.x * 128;
    const int b0 = base[e];

    __shared__ __align__(16) unsigned short Xs[128 * 64];
    __shared__ __align__(16) unsigned short W1s[128 * 64];
    __shared__ __align__(16) unsigned short W3s[128 * 64];

    const int tid = threadIdx.x;
    const int wv = tid >> 6, lane = tid & 63;
    const int trb = wv * 8 + (lane >> 3);   // tile row this lane stages (per it: +32)
    const int cph = lane & 7;               // physical 16B chunk

    // token index per staged X row (fixed across k0)
    int tokr[4];
#pragma unroll
    for (int it = 0; it < 4; it++) {
        int r = m0 + trb + it * 32;
        if (r >= cnt) r = cnt - 1;
        tokr[it] = (int)(rowtok[e * T_TOK + r] >> 1);
    }

    const int lr = lane & 15, lq = lane >> 4;
    const int wm = (wv >> 1) * 64, wn = (wv & 1) * 64;

    f32x4 accG[4][4], accU[4][4];
#pragma unroll
    for (int i = 0; i < 4; i++)
#pragma unroll
        for (int j = 0; j < 4; j++) {
            accG[i][j] = (f32x4){0.f, 0.f, 0.f, 0.f};
            accU[i][j] = (f32x4){0.f, 0.f, 0.f, 0.f};
        }

    const size_t wrow0 = (size_t)e * I_DIM + n0;

    for (int k0 = 0; k0 < H_DIM; k0 += 64) {
#pragma unroll
        for (int it = 0; it < 4; it++) {
            int tr = trb + it * 32;
            int csrc = (cph ^ (tr & 7)) * 8;        // logical source chunk (elems)
            int lo = tr * 64 + cph * 8;             // LDS elem offset (lane-contig)
            gl_lds16(Xb + (size_t)tokr[it] * H_DIM + k0 + csrc, &Xs[lo]);
            size_t wo = (wrow0 + tr) * H_DIM + k0 + csrc;
            gl_lds16(W1b + wo, &W1s[lo]);
            gl_lds16(W3b + wo, &W3s[lo]);
        }
        __syncthreads();
#pragma unroll
        for (int kk = 0; kk < 64; kk += 32) {
            const int qb = (kk >> 3) + lq;          // logical chunk for this frag
            bf16x8 a[4], b1[4], b3[4];
#pragma unroll
            for (int mi = 0; mi < 4; mi++) {
                int R = wm + mi * 16 + lr;
                a[mi] = *(const bf16x8*)&Xs[R * 64 + ((qb ^ (R & 7)) << 3)];
            }
#pragma unroll
            for (int ni = 0; ni < 4; ni++) {
                int R = wn + ni * 16 + lr;
                int off = R * 64 + ((qb ^ (R & 7)) << 3);
                b1[ni] = *(const bf16x8*)&W1s[off];
                b3[ni] = *(const bf16x8*)&W3s[off];
            }
#pragma unroll
            for (int ni = 0; ni < 4; ni++)
#pragma unroll
                for (int mi = 0; mi < 4; mi++) {
                    accG[mi][ni] = __builtin_amdgcn_mfma_f32_16x16x32_bf16(
                        a[mi], b1[ni], accG[mi][ni], 0, 0, 0);
                    accU[mi][ni] = __builtin_amdgcn_mfma_f32_16x16x32_bf16(
                        a[mi], b3[ni], accU[mi][ni], 0, 0, 0);
                }
        }
        __syncthreads();
    }

#pragma unroll
    for (int mi = 0; mi < 4; mi++) {
#pragma unroll
        for (int rg = 0; rg < 4; rg++) {
            int row = m0 + wm + mi * 16 + lq * 4 + rg;
            if (row < cnt) {
                size_t orow = (size_t)(b0 + row) * I_DIM + n0 + wn;
#pragma unroll
                for (int ni = 0; ni < 4; ni++) {
                    float g = accG[mi][ni][rg];
                    float u = accU[mi][ni][rg];
                    Aout[orow + ni * 16 + lr] = f2b((g / (1.f + __expf(-g))) * u);
                }
            }
        }
    }
}

// down GEMM, fast: 64x128 tile, BK=64, 4 waves (2x2 of 32x64).
// Epilogue: out[t] += w * acc (fp32 atomics; out pre-zeroed).
__global__ __launch_bounds__(256) void k_down_f(
    const unsigned short* __restrict__ Ab,
    const unsigned short* __restrict__ W2b,
    const int* __restrict__ counts, const int* __restrict__ base,
    const unsigned int* __restrict__ rowtok,
    const float* __restrict__ weight,
    float* __restrict__ out) {
    const int e = blockIdx.z;
    const int cnt = counts[e];
    const int m0 = blockIdx.y * 64;
    if (m0 >= cnt) return;
    const int n0 = blockIdx.x * 128;
    const int b0 = base[e];

    __shared__ __align__(16) unsigned short As[64 * 64];
    __shared__ __align__(16) unsigned short Ws[128 * 64];

    const int tid = threadIdx.x;
    const int wv = tid >> 6, lane = tid & 63;
    const int trb = wv * 8 + (lane >> 3);
    const int cph = lane & 7;

    int arow[2];
#pragma unroll
    for (int it = 0; it < 2; it++) {
        int r = m0 + trb + it * 32;
        if (r >= cnt) r = cnt - 1;
        arow[it] = b0 + r;
    }

    const int lr = lane & 15, lq = lane >> 4;
    const int wm = (wv >> 1) * 32, wn = (wv & 1) * 64;

    f32x4 acc[2][4];
#pragma unroll
    for (int i = 0; i < 2; i++)
#pragma unroll
        for (int j = 0; j < 4; j++) acc[i][j] = (f32x4){0.f, 0.f, 0.f, 0.f};

    const size_t wrow0 = (size_t)e * H_DIM + n0;

    for (int k0 = 0; k0 < I_DIM; k0 += 64) {
#pragma unroll
        for (int it = 0; it < 2; it++) {
            int tr = trb + it * 32;
            int csrc = (cph ^ (tr & 7)) * 8;
            gl_lds16(Ab + (size_t)arow[it] * I_DIM + k0 + csrc,
                     &As[tr * 64 + cph * 8]);
        }
#pragma unroll
        for (int it = 0; it < 4; it++) {
            int tr = trb + it * 32;
            int csrc = (cph ^ (tr & 7)) * 8;
            gl_lds16(W2b + (wrow0 + tr) * I_DIM + k0 + csrc,
                     &Ws[tr * 64 + cph * 8]);
        }
        __syncthreads();
#pragma unroll
        for (int kk = 0; kk < 64; kk += 32) {
            const int qb = (kk >> 3) + lq;
            bf16x8 a[2], b[4];
#pragma unroll
            for (int mi = 0; mi < 2; mi++) {
                int R = wm + mi * 16 + lr;
                a[mi] = *(const bf16x8*)&As[R * 64 + ((qb ^ (R & 7)) << 3)];
            }
#pragma unroll
            for (int ni = 0; ni < 4; ni++) {
                int R = wn + ni * 16 + lr;
                b[ni] = *(const bf16x8*)&Ws[R * 64 + ((qb ^ (R & 7)) << 3)];
            }
#pragma unroll
            for (int ni = 0; ni < 4; ni++)
#pragma unroll
                for (int mi = 0; mi < 2; mi++)
                    acc[mi][ni] = __builtin_amdgcn_mfma_f32_16x16x32_bf16(
                        a[mi], b[ni], acc[mi][ni], 0, 0, 0);
        }
        __syncthreads();
    }

#pragma unroll
    for (int mi = 0; mi < 2; mi++) {
#pragma unroll
        for (int rg = 0; rg < 4; rg++) {
            int row = m0 + wm + mi * 16 + lq * 4 + rg;
            if (row < cnt) {
                unsigned rt = rowtok[e * T_TOK + row];
                float w = weight[rt];
                float* op = out + (size_t)(rt >> 1) * H_DIM + n0 + wn;
#pragma unroll
                for (int ni = 0; ni < 4; ni++)
                    atomicAdd(op + ni * 16 + lr, w * acc[mi][ni][rg]);
            }
        }
    }
}

// -------- fallback path (R1, known-passing) --------
#define BK 64
#define LDSP 72

__global__ __launch_bounds__(256) void k_gate_up_s(
    const float* __restrict__ X, const float* __restrict__ W1,
    const float* __restrict__ W3,
    const int* __restrict__ counts, const int* __restrict__ base,
    const unsigned int* __restrict__ rowtok,
    unsigned short* __restrict__ Aout) {
    const int e = blockIdx.z;
    const int cnt = counts[e];
    const int m0 = blockIdx.y * 64;
    if (m0 >= cnt) return;
    const int n0 = blockIdx.x * 128;
    const int b0 = base[e];
    __shared__ unsigned short Xs[64][LDSP];
    __shared__ unsigned short W1s[128][LDSP];
    __shared__ unsigned short W3s[128][LDSP];
    __shared__ int toks[64];
    const int tid = threadIdx.x;
    if (tid < 64) {
        int r = m0 + tid;
        if (r >= cnt) r = cnt - 1;
        toks[tid] = (int)(rowtok[e * T_TOK + r] >> 1);
    }
    __syncthreads();
    const int wv = tid >> 6, lane = tid & 63;
    const int lr = lane & 15, lq = lane >> 4;
    const int wm = (wv >> 1) * 32, wn = (wv & 1) * 64;
    f32x4 accG[2][4], accU[2][4];
#pragma unroll
    for (int i = 0; i < 2; i++)
#pragma unroll
        for (int j = 0; j < 4; j++) {
            accG[i][j] = (f32x4){0.f, 0.f, 0.f, 0.f};
            accU[i][j] = (f32x4){0.f, 0.f, 0.f, 0.f};
        }
    const size_t wbase = ((size_t)e * I_DIM + n0) * H_DIM;
    for (int k0 = 0; k0 < H_DIM; k0 += BK) {
#pragma unroll
        for (int it = 0; it < 2; ++it) {
            int idx = tid + it * 256;
            int r = idx >> 3, c = (idx & 7) * 8;
            *(bf16x8*)&Xs[r][c] = cvt8(X + (size_t)toks[r] * H_DIM + k0 + c);
        }
#pragma unroll
        for (int it = 0; it < 4; ++it) {
            int idx = tid + it * 256;
            int r = idx >> 3, c = (idx & 7) * 8;
            size_t off = wbase + (size_t)r * H_DIM + k0 + c;
            *(bf16x8*)&W1s[r][c] = cvt8(W1 + off);
            *(bf16x8*)&W3s[r][c] = cvt8(W3 + off);
        }
        __syncthreads();
#pragma unroll
        for (int kk = 0; kk < BK; kk += 32) {
            bf16x8 af[2];
#pragma unroll
            for (int mi = 0; mi < 2; mi++)
                af[mi] = *(const bf16x8*)&Xs[wm + mi * 16 + lr][kk + lq * 8];
#pragma unroll
            for (int ni = 0; ni < 4; ni++) {
                bf16x8 b1 = *(const bf16x8*)&W1s[wn + ni * 16 + lr][kk + lq * 8];
                bf16x8 b3 = *(const bf16x8*)&W3s[wn + ni * 16 + lr][kk + lq * 8];
#pragma unroll
                for (int mi = 0; mi < 2; mi++) {
                    accG[mi][ni] = __builtin_amdgcn_mfma_f32_16x16x32_bf16(
                        af[mi], b1, accG[mi][ni], 0, 0, 0);
                    accU[mi][ni] = __builtin_amdgcn_mfma_f32_16x16x32_bf16(
                        af[mi], b3, accU[mi][ni], 0, 0, 0);
                }
            }
        }
        __syncthreads();
    }
#pragma unroll
    for (int mi = 0; mi < 2; mi++) {
#pragma unroll
        for (int r = 0; r < 4; r++) {
            int row = m0 + wm + mi * 16 + lq * 4 + r;
            if (row < cnt) {
                size_t orow = (size_t)(b0 + row) * I_DIM + n0 + wn;
#pragma unroll
                for (int ni = 0; ni < 4; ni++) {
                    float g = accG[mi][ni][r];
                    float u = accU[mi][ni][r];
                    Aout[orow + ni * 16 + lr] = f2b((g / (1.f + __expf(-g))) * u);
                }
            }
        }
    }
}

__global__ __launch_bounds__(256) void k_down_s(
    const unsigned short* __restrict__ A, const float* __restrict__ W2,
    const int* __restrict__ counts, const int* __restrict__ base,
    const unsigned int* __restrict__ rowtok,
    const float* __restrict__ weight, float* __restrict__ Y) {
    const int e = blockIdx.z;
    const int cnt = counts[e];
    const int m0 = blockIdx.y * 64;
    if (m0 >= cnt) return;
    const int n0 = blockIdx.x * 128;
    const int b0 = base[e];
    __shared__ unsigned short As[64][LDSP];
    __shared__ unsigned short Ws[128][LDSP];
    const int tid = threadIdx.x;
    const int wv = tid >> 6, lane = tid & 63;
    const int lr = lane & 15, lq = lane >> 4;
    const int wm = (wv >> 1) * 32, wn = (wv & 1) * 64;
    f32x4 acc[2][4];
#pragma unroll
    for (int i = 0; i < 2; i++)
#pragma unroll
        for (int j = 0; j < 4; j++) acc[i][j] = (f32x4){0.f, 0.f, 0.f, 0.f};
    const size_t wbase = ((size_t)e * H_DIM + n0) * I_DIM;
    for (int k0 = 0; k0 < I_DIM; k0 += BK) {
#pragma unroll
        for (int it = 0; it < 2; ++it) {
            int idx = tid + it * 256;
            int r = idx >> 3, c = (idx & 7) * 8;
            int rr = m0 + r;
            if (rr >= cnt) rr = cnt - 1;
            *(bf16x8*)&As[r][c] =
                *(const bf16x8*)(A + (size_t)(b0 + rr) * I_DIM + k0 + c);
        }
#pragma unroll
        for (int it = 0; it < 4; ++it) {
            int idx = tid + it * 256;
            int r = idx >> 3, c = (idx & 7) * 8;
            *(bf16x8*)&Ws[r][c] = cvt8(W2 + wbase + (size_t)r * I_DIM + k0 + c);
        }
        __syncthreads();
#pragma unroll
        for (int kk = 0; kk < BK; kk += 32) {
            bf16x8 af[2];
#pragma unroll
            for (int mi = 0; mi < 2; mi++)
                af[mi] = *(const bf16x8*)&As[wm + mi * 16 + lr][kk + lq * 8];
#pragma unroll
            for (int ni = 0; ni < 4; ni++) {
                bf16x8 b = *(const bf16x8*)&Ws[wn + ni * 16 + lr][kk + lq * 8];
#pragma unroll
                for (int mi = 0; mi < 2; mi++)
                    acc[mi][ni] = __builtin_amdgcn_mfma_f32_16x16x32_bf16(
                        af[mi], b, acc[mi][ni], 0, 0, 0);
            }
        }
        __syncthreads();
    }
#pragma unroll
    for (int mi = 0; mi < 2; mi++) {
#pragma unroll
        for (int r = 0; r < 4; r++) {
            int row = m0 + wm + mi * 16 + lq * 4 + r;
            if (row < cnt) {
                unsigned rt = rowtok[e * T_TOK + row];
                float w = weight[rt];
                size_t orow = (size_t)rt * H_DIM + n0 + wn;
#pragma unroll
                for (int ni = 0; ni < 4; ni++)
                    Y[orow + ni * 16 + lr] = w * acc[mi][ni][r];
            }
        }
    }
}

__global__ void k_combine(const float* __restrict__ Y, float* __restrict__ out) {
    int g = blockIdx.x * blockDim.x + threadIdx.x;
    int t = g >> 8, c4 = g & 255;
    const float4* y0 = (const float4*)(Y + (size_t)(t * 2) * H_DIM);
    const float4* y1 = (const float4*)(Y + (size_t)(t * 2 + 1) * H_DIM);
    float4 a = y0[c4], b = y1[c4];
    float4 o;
    o.x = a.x + b.x; o.y = a.y + b.y; o.z = a.z + b.z; o.w = a.w + b.w;
    *(float4*)(out + (size_t)t * H_DIM + c4 * 4) = o;
}

extern "C" void kernel_launch(void* const* d_in, const int* in_sizes, int n_in,
                              void* d_out, int out_size, void* d_ws, size_t ws_size,
                              hipStream_t stream) {
    (void)in_sizes; (void)n_in; (void)out_size;
    const float* X  = (const float*)d_in[0];
    const float* RL = (const float*)d_in[1];
    const float* W1 = (const float*)d_in[2];
    const float* W3 = (const float*)d_in[3];
    const float* W2 = (const float*)d_in[4];
    float* out = (float*)d_out;

    char* ws = (char*)d_ws;
    int* counts          = (int*)(ws + WS_COUNTS);
    int* base            = (int*)(ws + WS_BASE);
    unsigned int* rowtok = (unsigned int*)(ws + WS_ROWTOK);
    float* weight        = (float*)(ws + WS_WEIGHT);

    hipMemsetAsync(counts, 0, 64, stream);
    hipLaunchKernelGGL(k_route, dim3(T_TOK / 256), dim3(256), 0, stream,
                       RL, counts, rowtok, weight);
    hipLaunchKernelGGL(k_prefix, dim3(1), dim3(64), 0, stream, counts, base);

    if (ws_size >= WSF_NEED) {
        unsigned short* Xb  = (unsigned short*)(ws + WSF_X);
        unsigned short* W1b = (unsigned short*)(ws + WSF_W1);
        unsigned short* W3b = (unsigned short*)(ws + WSF_W3);
        unsigned short* W2b = (unsigned short*)(ws + WSF_W2);
        unsigned short* Ab  = (unsigned short*)(ws + WSF_A);
        hipMemsetAsync(out, 0, (size_t)T_TOK * H_DIM * 4, stream);
        hipLaunchKernelGGL(k_cvt, dim3(34816), dim3(256), 0, stream,
                           W1, W3, W2, X, W1b, W3b, W2b, Xb);
        hipLaunchKernelGGL(k_gate_up_f, dim3(I_DIM / 128, 16, E_NUM), dim3(256),
                           0, stream, Xb, W1b, W3b, counts, base, rowtok, Ab);
        hipLaunchKernelGGL(k_down_f, dim3(H_DIM / 128, 32, E_NUM), dim3(256),
                           0, stream, Ab, W2b, counts, base, rowtok, weight, out);
    } else {
        unsigned short* Aact = (unsigned short*)(ws + WS_ACT);
        float* Y             = (float*)(ws + WS_Y);
        hipLaunchKernelGGL(k_gate_up_s, dim3(I_DIM / 128, T_TOK / 64, E_NUM),
                           dim3(256), 0, stream, X, W1, W3, counts, base, rowtok, Aact);
        hipLaunchKernelGGL(k_down_s, dim3(H_DIM / 128, T_TOK / 64, E_NUM),
                           dim3(256), 0, stream, Aact, W2, counts, base, rowtok,
                           weight, Y);
        hipLaunchKernelGGL(k_combine, dim3(T_TOK), dim3(256), 0, stream, Y, out);
    }
}

// Round 4
// 456.849 us; speedup vs baseline: 1.6421x; 1.1360x over previous
//
#include <hip/hip_runtime.h>
#include <hip/hip_bf16.h>
#include <math.h>

// Mixtral-style top-2 MoE. T=2048, H=1024, I=2816, E=8, top_k=2.
// All inputs/outputs fp32. Fast path: pre-convert W,X to bf16 in ws, then
// MFMA GEMMs (global_load_lds width=16, XOR-swizzled LDS).
// R3: gate_up tile 128x64 (dual 64x32/wave, 64 AGPR) to fix occupancy cliff;
//     down writes Y (overlaid on dead W1b region) + combine, no atomics.

#define T_TOK 2048
#define H_DIM 1024
#define I_DIM 2816
#define E_NUM 8

typedef __attribute__((ext_vector_type(8))) short bf16x8;
typedef __attribute__((ext_vector_type(4))) float f32x4;

// ---- shared low ws region ----
#define WS_COUNTS 0
#define WS_BASE   64
#define WS_ROWTOK 1024
#define WS_WEIGHT 66560
// ---- fast path ws ----
#define WSF_X   131072ull                       // bf16 X  [2048][1024]   4 MB
#define WSF_W1  (WSF_X  + 4194304ull)           // bf16 W1 [8][2816][1024] 46.1 MB
#define WSF_W3  (WSF_W1 + 46137344ull)
#define WSF_W2  (WSF_W3 + 46137344ull)
#define WSF_A   (WSF_W2 + 46137344ull)          // bf16 A  [4096][2816]  23.1 MB
#define WSF_NEED (WSF_A + 23068672ull)          // = 165,806,080 B
#define WSF_Y   WSF_W1   // fp32 Y [4096][1024] 16.8 MB, overlays W1b (dead after gate_up)
// ---- fallback ws ----
#define WS_ACT    131072ull
#define WS_Y      (131072ull + 23068672ull)

__device__ __forceinline__ unsigned short f2b(float f) {
    union { float f; unsigned int i; } c;
    c.f = f;
    unsigned int x = c.i;
    unsigned int r = x + 0x7FFFu + ((x >> 16) & 1u);  // RNE
    return (unsigned short)(r >> 16);
}

__device__ __forceinline__ bf16x8 cvt8(const float* __restrict__ p) {
    float4 a = *(const float4*)p;
    float4 b = *(const float4*)(p + 4);
    bf16x8 o;
    o[0] = (short)f2b(a.x); o[1] = (short)f2b(a.y);
    o[2] = (short)f2b(a.z); o[3] = (short)f2b(a.w);
    o[4] = (short)f2b(b.x); o[5] = (short)f2b(b.y);
    o[6] = (short)f2b(b.z); o[7] = (short)f2b(b.w);
    return o;
}

// async global->LDS, 16 bytes per lane. LDS dst must be wave-uniform base + lane*16.
__device__ __forceinline__ void gl_lds16(const void* g, void* l) {
    __builtin_amdgcn_global_load_lds(
        (const __attribute__((address_space(1))) unsigned int*)g,
        (__attribute__((address_space(3))) unsigned int*)l, 16, 0, 0);
}

// -------- 1. routing --------
__global__ void k_route(const float* __restrict__ logits,
                        int* __restrict__ counts,
                        unsigned int* __restrict__ rowtok,
                        float* __restrict__ weight) {
    int t = blockIdx.x * blockDim.x + threadIdx.x;
    if (t >= T_TOK) return;
    const float* p = logits + t * E_NUM;
    float l[E_NUM];
#pragma unroll
    for (int i = 0; i < E_NUM; i++) l[i] = p[i];
    float m = l[0];
#pragma unroll
    for (int i = 1; i < E_NUM; i++) m = fmaxf(m, l[i]);
    float e[E_NUM];
#pragma unroll
    for (int i = 0; i < E_NUM; i++) e[i] = expf(l[i] - m);
    int i0 = 0; float p0 = e[0];
#pragma unroll
    for (int i = 1; i < E_NUM; i++) if (e[i] > p0) { p0 = e[i]; i0 = i; }
    int i1 = -1; float p1 = -1.f;
#pragma unroll
    for (int i = 0; i < E_NUM; i++) if (i != i0 && e[i] > p1) { p1 = e[i]; i1 = i; }
    float s = p0 + p1;
    weight[t * 2 + 0] = p0 / s;
    weight[t * 2 + 1] = p1 / s;
    int q0 = atomicAdd(&counts[i0], 1);
    rowtok[i0 * T_TOK + q0] = (unsigned)(t * 2 + 0);
    int q1 = atomicAdd(&counts[i1], 1);
    rowtok[i1 * T_TOK + q1] = (unsigned)(t * 2 + 1);
}

// -------- 2. prefix --------
__global__ void k_prefix(const int* __restrict__ counts, int* __restrict__ base) {
    if (threadIdx.x == 0) {
        int s = 0;
        for (int e = 0; e < E_NUM; e++) { base[e] = s; s += counts[e]; }
    }
}

// -------- fast path --------

// fp32 -> bf16 bulk convert: W1,W3,W2 (11264 blocks each), X (1024 blocks)
__global__ __launch_bounds__(256) void k_cvt(
    const float* __restrict__ W1, const float* __restrict__ W3,
    const float* __restrict__ W2, const float* __restrict__ X,
    unsigned short* __restrict__ W1b, unsigned short* __restrict__ W3b,
    unsigned short* __restrict__ W2b, unsigned short* __restrict__ Xb) {
    int b = blockIdx.x;
    const float* src; unsigned short* dst; int lb;
    if (b < 11264)      { src = W1; dst = W1b; lb = b; }
    else if (b < 22528) { src = W3; dst = W3b; lb = b - 11264; }
    else if (b < 33792) { src = W2; dst = W2b; lb = b - 22528; }
    else                { src = X;  dst = Xb;  lb = b - 33792; }
    size_t i = ((size_t)lb * 256 + threadIdx.x) * 8;
    *(bf16x8*)(dst + i) = cvt8(src + i);
}

// gate/up GEMM: block tile 128(M)x64(N), BK=64, 4 waves 2x2, wave = dual 64x32.
// LDS XOR-swizzled: physical 16B-chunk = logical ^ (row&7).
__global__ __launch_bounds__(256) void k_gate_up_f(
    const unsigned short* __restrict__ Xb,
    const unsigned short* __restrict__ W1b,
    const unsigned short* __restrict__ W3b,
    const int* __restrict__ counts, const int* __restrict__ base,
    const unsigned int* __restrict__ rowtok,
    unsigned short* __restrict__ Aout) {
    const int e = blockIdx.z;
    const int cnt = counts[e];
    const int m0 = blockIdx.y * 128;
    if (m0 >= cnt) return;
    const int n0 = blockIdx.x * 64;
    const int b0 = base[e];

    __shared__ __align__(16) unsigned short Xs[128 * 64];
    __shared__ __align__(16) unsigned short W1s[64 * 64];
    __shared__ __align__(16) unsigned short W3s[64 * 64];

    const int tid = threadIdx.x;
    const int wv = tid >> 6, lane = tid & 63;
    const int trb = wv * 8 + (lane >> 3);   // staging row (per it: +32)
    const int cph = lane & 7;               // physical 16B chunk

    int tokr[4];
#pragma unroll
    for (int it = 0; it < 4; it++) {
        int r = m0 + trb + it * 32;
        if (r >= cnt) r = cnt - 1;
        tokr[it] = (int)(rowtok[e * T_TOK + r] >> 1);
    }

    const int lr = lane & 15, lq = lane >> 4;
    const int wm = (wv >> 1) * 64, wn = (wv & 1) * 32;

    f32x4 accG[4][2], accU[4][2];
#pragma unroll
    for (int i = 0; i < 4; i++)
#pragma unroll
        for (int j = 0; j < 2; j++) {
            accG[i][j] = (f32x4){0.f, 0.f, 0.f, 0.f};
            accU[i][j] = (f32x4){0.f, 0.f, 0.f, 0.f};
        }

    const size_t wrow0 = (size_t)e * I_DIM + n0;

    for (int k0 = 0; k0 < H_DIM; k0 += 64) {
#pragma unroll
        for (int it = 0; it < 4; it++) {
            int tr = trb + it * 32;
            int csrc = (cph ^ (tr & 7)) * 8;
            gl_lds16(Xb + (size_t)tokr[it] * H_DIM + k0 + csrc,
                     &Xs[tr * 64 + cph * 8]);
        }
#pragma unroll
        for (int it = 0; it < 2; it++) {
            int tr = trb + it * 32;
            int csrc = (cph ^ (tr & 7)) * 8;
            int lo = tr * 64 + cph * 8;
            size_t wo = (wrow0 + tr) * H_DIM + k0 + csrc;
            gl_lds16(W1b + wo, &W1s[lo]);
            gl_lds16(W3b + wo, &W3s[lo]);
        }
        __syncthreads();
#pragma unroll
        for (int kk = 0; kk < 64; kk += 32) {
            const int qb = (kk >> 3) + lq;
            bf16x8 a[4], b1[2], b3[2];
#pragma unroll
            for (int mi = 0; mi < 4; mi++) {
                int R = wm + mi * 16 + lr;
                a[mi] = *(const bf16x8*)&Xs[R * 64 + ((qb ^ (R & 7)) << 3)];
            }
#pragma unroll
            for (int ni = 0; ni < 2; ni++) {
                int R = wn + ni * 16 + lr;
                int off = R * 64 + ((qb ^ (R & 7)) << 3);
                b1[ni] = *(const bf16x8*)&W1s[off];
                b3[ni] = *(const bf16x8*)&W3s[off];
            }
#pragma unroll
            for (int ni = 0; ni < 2; ni++)
#pragma unroll
                for (int mi = 0; mi < 4; mi++) {
                    accG[mi][ni] = __builtin_amdgcn_mfma_f32_16x16x32_bf16(
                        a[mi], b1[ni], accG[mi][ni], 0, 0, 0);
                    accU[mi][ni] = __builtin_amdgcn_mfma_f32_16x16x32_bf16(
                        a[mi], b3[ni], accU[mi][ni], 0, 0, 0);
                }
        }
        __syncthreads();
    }

#pragma unroll
    for (int mi = 0; mi < 4; mi++) {
#pragma unroll
        for (int rg = 0; rg < 4; rg++) {
            int row = m0 + wm + mi * 16 + lq * 4 + rg;
            if (row < cnt) {
                size_t orow = (size_t)(b0 + row) * I_DIM + n0 + wn;
#pragma unroll
                for (int ni = 0; ni < 2; ni++) {
                    float g = accG[mi][ni][rg];
                    float u = accU[mi][ni][rg];
                    Aout[orow + ni * 16 + lr] = f2b((g / (1.f + __expf(-g))) * u);
                }
            }
        }
    }
}

// down GEMM: 64x128 tile, BK=64, 4 waves (2x2 of 32x64). Writes w*acc to Y.
__global__ __launch_bounds__(256) void k_down_f(
    const unsigned short* __restrict__ Ab,
    const unsigned short* __restrict__ W2b,
    const int* __restrict__ counts, const int* __restrict__ base,
    const unsigned int* __restrict__ rowtok,
    const float* __restrict__ weight,
    float* __restrict__ Y) {
    const int e = blockIdx.z;
    const int cnt = counts[e];
    const int m0 = blockIdx.y * 64;
    if (m0 >= cnt) return;
    const int n0 = blockIdx.x * 128;
    const int b0 = base[e];

    __shared__ __align__(16) unsigned short As[64 * 64];
    __shared__ __align__(16) unsigned short Ws[128 * 64];

    const int tid = threadIdx.x;
    const int wv = tid >> 6, lane = tid & 63;
    const int trb = wv * 8 + (lane >> 3);
    const int cph = lane & 7;

    int arow[2];
#pragma unroll
    for (int it = 0; it < 2; it++) {
        int r = m0 + trb + it * 32;
        if (r >= cnt) r = cnt - 1;
        arow[it] = b0 + r;
    }

    const int lr = lane & 15, lq = lane >> 4;
    const int wm = (wv >> 1) * 32, wn = (wv & 1) * 64;

    f32x4 acc[2][4];
#pragma unroll
    for (int i = 0; i < 2; i++)
#pragma unroll
        for (int j = 0; j < 4; j++) acc[i][j] = (f32x4){0.f, 0.f, 0.f, 0.f};

    const size_t wrow0 = (size_t)e * H_DIM + n0;

    for (int k0 = 0; k0 < I_DIM; k0 += 64) {
#pragma unroll
        for (int it = 0; it < 2; it++) {
            int tr = trb + it * 32;
            int csrc = (cph ^ (tr & 7)) * 8;
            gl_lds16(Ab + (size_t)arow[it] * I_DIM + k0 + csrc,
                     &As[tr * 64 + cph * 8]);
        }
#pragma unroll
        for (int it = 0; it < 4; it++) {
            int tr = trb + it * 32;
            int csrc = (cph ^ (tr & 7)) * 8;
            gl_lds16(W2b + (wrow0 + tr) * I_DIM + k0 + csrc,
                     &Ws[tr * 64 + cph * 8]);
        }
        __syncthreads();
#pragma unroll
        for (int kk = 0; kk < 64; kk += 32) {
            const int qb = (kk >> 3) + lq;
            bf16x8 a[2], b[4];
#pragma unroll
            for (int mi = 0; mi < 2; mi++) {
                int R = wm + mi * 16 + lr;
                a[mi] = *(const bf16x8*)&As[R * 64 + ((qb ^ (R & 7)) << 3)];
            }
#pragma unroll
            for (int ni = 0; ni < 4; ni++) {
                int R = wn + ni * 16 + lr;
                b[ni] = *(const bf16x8*)&Ws[R * 64 + ((qb ^ (R & 7)) << 3)];
            }
#pragma unroll
            for (int ni = 0; ni < 4; ni++)
#pragma unroll
                for (int mi = 0; mi < 2; mi++)
                    acc[mi][ni] = __builtin_amdgcn_mfma_f32_16x16x32_bf16(
                        a[mi], b[ni], acc[mi][ni], 0, 0, 0);
        }
        __syncthreads();
    }

#pragma unroll
    for (int mi = 0; mi < 2; mi++) {
#pragma unroll
        for (int rg = 0; rg < 4; rg++) {
            int row = m0 + wm + mi * 16 + lq * 4 + rg;
            if (row < cnt) {
                unsigned rt = rowtok[e * T_TOK + row];
                float w = weight[rt];
                float* op = Y + (size_t)rt * H_DIM + n0 + wn;
#pragma unroll
                for (int ni = 0; ni < 4; ni++)
                    op[ni * 16 + lr] = w * acc[mi][ni][rg];
            }
        }
    }
}

// combine slots -> fp32 out
__global__ void k_combine(const float* __restrict__ Y, float* __restrict__ out) {
    int g = blockIdx.x * blockDim.x + threadIdx.x;
    int t = g >> 8, c4 = g & 255;
    const float4* y0 = (const float4*)(Y + (size_t)(t * 2) * H_DIM);
    const float4* y1 = (const float4*)(Y + (size_t)(t * 2 + 1) * H_DIM);
    float4 a = y0[c4], b = y1[c4];
    float4 o;
    o.x = a.x + b.x; o.y = a.y + b.y; o.z = a.z + b.z; o.w = a.w + b.w;
    *(float4*)(out + (size_t)t * H_DIM + c4 * 4) = o;
}

// -------- fallback path (R1, known-passing) --------
#define BK 64
#define LDSP 72

__global__ __launch_bounds__(256) void k_gate_up_s(
    const float* __restrict__ X, const float* __restrict__ W1,
    const float* __restrict__ W3,
    const int* __restrict__ counts, const int* __restrict__ base,
    const unsigned int* __restrict__ rowtok,
    unsigned short* __restrict__ Aout) {
    const int e = blockIdx.z;
    const int cnt = counts[e];
    const int m0 = blockIdx.y * 64;
    if (m0 >= cnt) return;
    const int n0 = blockIdx.x * 128;
    const int b0 = base[e];
    __shared__ unsigned short Xs[64][LDSP];
    __shared__ unsigned short W1s[128][LDSP];
    __shared__ unsigned short W3s[128][LDSP];
    __shared__ int toks[64];
    const int tid = threadIdx.x;
    if (tid < 64) {
        int r = m0 + tid;
        if (r >= cnt) r = cnt - 1;
        toks[tid] = (int)(rowtok[e * T_TOK + r] >> 1);
    }
    __syncthreads();
    const int wv = tid >> 6, lane = tid & 63;
    const int lr = lane & 15, lq = lane >> 4;
    const int wm = (wv >> 1) * 32, wn = (wv & 1) * 64;
    f32x4 accG[2][4], accU[2][4];
#pragma unroll
    for (int i = 0; i < 2; i++)
#pragma unroll
        for (int j = 0; j < 4; j++) {
            accG[i][j] = (f32x4){0.f, 0.f, 0.f, 0.f};
            accU[i][j] = (f32x4){0.f, 0.f, 0.f, 0.f};
        }
    const size_t wbase = ((size_t)e * I_DIM + n0) * H_DIM;
    for (int k0 = 0; k0 < H_DIM; k0 += BK) {
#pragma unroll
        for (int it = 0; it < 2; ++it) {
            int idx = tid + it * 256;
            int r = idx >> 3, c = (idx & 7) * 8;
            *(bf16x8*)&Xs[r][c] = cvt8(X + (size_t)toks[r] * H_DIM + k0 + c);
        }
#pragma unroll
        for (int it = 0; it < 4; ++it) {
            int idx = tid + it * 256;
            int r = idx >> 3, c = (idx & 7) * 8;
            size_t off = wbase + (size_t)r * H_DIM + k0 + c;
            *(bf16x8*)&W1s[r][c] = cvt8(W1 + off);
            *(bf16x8*)&W3s[r][c] = cvt8(W3 + off);
        }
        __syncthreads();
#pragma unroll
        for (int kk = 0; kk < BK; kk += 32) {
            bf16x8 af[2];
#pragma unroll
            for (int mi = 0; mi < 2; mi++)
                af[mi] = *(const bf16x8*)&Xs[wm + mi * 16 + lr][kk + lq * 8];
#pragma unroll
            for (int ni = 0; ni < 4; ni++) {
                bf16x8 b1 = *(const bf16x8*)&W1s[wn + ni * 16 + lr][kk + lq * 8];
                bf16x8 b3 = *(const bf16x8*)&W3s[wn + ni * 16 + lr][kk + lq * 8];
#pragma unroll
                for (int mi = 0; mi < 2; mi++) {
                    accG[mi][ni] = __builtin_amdgcn_mfma_f32_16x16x32_bf16(
                        af[mi], b1, accG[mi][ni], 0, 0, 0);
                    accU[mi][ni] = __builtin_amdgcn_mfma_f32_16x16x32_bf16(
                        af[mi], b3, accU[mi][ni], 0, 0, 0);
                }
            }
        }
        __syncthreads();
    }
#pragma unroll
    for (int mi = 0; mi < 2; mi++) {
#pragma unroll
        for (int r = 0; r < 4; r++) {
            int row = m0 + wm + mi * 16 + lq * 4 + r;
            if (row < cnt) {
                size_t orow = (size_t)(b0 + row) * I_DIM + n0 + wn;
#pragma unroll
                for (int ni = 0; ni < 4; ni++) {
                    float g = accG[mi][ni][r];
                    float u = accU[mi][ni][r];
                    Aout[orow + ni * 16 + lr] = f2b((g / (1.f + __expf(-g))) * u);
                }
            }
        }
    }
}

__global__ __launch_bounds__(256) void k_down_s(
    const unsigned short* __restrict__ A, const float* __restrict__ W2,
    const int* __restrict__ counts, const int* __restrict__ base,
    const unsigned int* __restrict__ rowtok,
    const float* __restrict__ weight, float* __restrict__ Y) {
    const int e = blockIdx.z;
    const int cnt = counts[e];
    const int m0 = blockIdx.y * 64;
    if (m0 >= cnt) return;
    const int n0 = blockIdx.x * 128;
    const int b0 = base[e];
    __shared__ unsigned short As[64][LDSP];
    __shared__ unsigned short Ws[128][LDSP];
    const int tid = threadIdx.x;
    const int wv = tid >> 6, lane = tid & 63;
    const int lr = lane & 15, lq = lane >> 4;
    const int wm = (wv >> 1) * 32, wn = (wv & 1) * 64;
    f32x4 acc[2][4];
#pragma unroll
    for (int i = 0; i < 2; i++)
#pragma unroll
        for (int j = 0; j < 4; j++) acc[i][j] = (f32x4){0.f, 0.f, 0.f, 0.f};
    const size_t wbase = ((size_t)e * H_DIM + n0) * I_DIM;
    for (int k0 = 0; k0 < I_DIM; k0 += BK) {
#pragma unroll
        for (int it = 0; it < 2; ++it) {
            int idx = tid + it * 256;
            int r = idx >> 3, c = (idx & 7) * 8;
            int rr = m0 + r;
            if (rr >= cnt) rr = cnt - 1;
            *(bf16x8*)&As[r][c] =
                *(const bf16x8*)(A + (size_t)(b0 + rr) * I_DIM + k0 + c);
        }
#pragma unroll
        for (int it = 0; it < 4; ++it) {
            int idx = tid + it * 256;
            int r = idx >> 3, c = (idx & 7) * 8;
            *(bf16x8*)&Ws[r][c] = cvt8(W2 + wbase + (size_t)r * I_DIM + k0 + c);
        }
        __syncthreads();
#pragma unroll
        for (int kk = 0; kk < BK; kk += 32) {
            bf16x8 af[2];
#pragma unroll
            for (int mi = 0; mi < 2; mi++)
                af[mi] = *(const bf16x8*)&As[wm + mi * 16 + lr][kk + lq * 8];
#pragma unroll
            for (int ni = 0; ni < 4; ni++) {
                bf16x8 b = *(const bf16x8*)&Ws[wn + ni * 16 + lr][kk + lq * 8];
#pragma unroll
                for (int mi = 0; mi < 2; mi++)
                    acc[mi][ni] = __builtin_amdgcn_mfma_f32_16x16x32_bf16(
                        af[mi], b, acc[mi][ni], 0, 0, 0);
            }
        }
        __syncthreads();
    }
#pragma unroll
    for (int mi = 0; mi < 2; mi++) {
#pragma unroll
        for (int r = 0; r < 4; r++) {
            int row = m0 + wm + mi * 16 + lq * 4 + r;
            if (row < cnt) {
                unsigned rt = rowtok[e * T_TOK + row];
                float w = weight[rt];
                size_t orow = (size_t)rt * H_DIM + n0 + wn;
#pragma unroll
                for (int ni = 0; ni < 4; ni++)
                    Y[orow + ni * 16 + lr] = w * acc[mi][ni][r];
            }
        }
    }
}

extern "C" void kernel_launch(void* const* d_in, const int* in_sizes, int n_in,
                              void* d_out, int out_size, void* d_ws, size_t ws_size,
                              hipStream_t stream) {
    (void)in_sizes; (void)n_in; (void)out_size;
    const float* X  = (const float*)d_in[0];
    const float* RL = (const float*)d_in[1];
    const float* W1 = (const float*)d_in[2];
    const float* W3 = (const float*)d_in[3];
    const float* W2 = (const float*)d_in[4];
    float* out = (float*)d_out;

    char* ws = (char*)d_ws;
    int* counts          = (int*)(ws + WS_COUNTS);
    int* base            = (int*)(ws + WS_BASE);
    unsigned int* rowtok = (unsigned int*)(ws + WS_ROWTOK);
    float* weight        = (float*)(ws + WS_WEIGHT);

    hipMemsetAsync(counts, 0, 64, stream);
    hipLaunchKernelGGL(k_route, dim3(T_TOK / 256), dim3(256), 0, stream,
                       RL, counts, rowtok, weight);
    hipLaunchKernelGGL(k_prefix, dim3(1), dim3(64), 0, stream, counts, base);

    if (ws_size >= WSF_NEED) {
        unsigned short* Xb  = (unsigned short*)(ws + WSF_X);
        unsigned short* W1b = (unsigned short*)(ws + WSF_W1);
        unsigned short* W3b = (unsigned short*)(ws + WSF_W3);
        unsigned short* W2b = (unsigned short*)(ws + WSF_W2);
        unsigned short* Ab  = (unsigned short*)(ws + WSF_A);
        float* Y            = (float*)(ws + WSF_Y);   // overlays W1b (dead after gate_up)
        hipLaunchKernelGGL(k_cvt, dim3(34816), dim3(256), 0, stream,
                           W1, W3, W2, X, W1b, W3b, W2b, Xb);
        hipLaunchKernelGGL(k_gate_up_f, dim3(I_DIM / 64, 16, E_NUM), dim3(256),
                           0, stream, Xb, W1b, W3b, counts, base, rowtok, Ab);
        hipLaunchKernelGGL(k_down_f, dim3(H_DIM / 128, 32, E_NUM), dim3(256),
                           0, stream, Ab, W2b, counts, base, rowtok, weight, Y);
        hipLaunchKernelGGL(k_combine, dim3(T_TOK), dim3(256), 0, stream, Y, out);
    } else {
        unsigned short* Aact = (unsigned short*)(ws + WS_ACT);
        float* Y             = (float*)(ws + WS_Y);
        hipLaunchKernelGGL(k_gate_up_s, dim3(I_DIM / 128, T_TOK / 64, E_NUM),
                           dim3(256), 0, stream, X, W1, W3, counts, base, rowtok, Aact);
        hipLaunchKernelGGL(k_down_s, dim3(H_DIM / 128, T_TOK / 64, E_NUM),
                           dim3(256), 0, stream, Aact, W2, counts, base, rowtok,
                           weight, Y);
        hipLaunchKernelGGL(k_combine, dim3(T_TOK), dim3(256), 0, stream, Y, out);
    }
}